// Round 4
// baseline (42729.691 us; speedup 1.0000x reference)
//
#include <hip/hip_runtime.h>

#define BB 256
#define TT 2048
#define HH 128
#define G4 512     // 4*H gate rows
#define INW 4
#define OUTW 4
#define TC 56      // time-chunk; LDS-resident
#define NT 1024    // 2 threads per gate row; 64 weights each
#define HW 64      // half-row width

__device__ __forceinline__ float sigm(float x) {
    return __fdividef(1.f, 1.f + __expf(-x));
}
__device__ __forceinline__ float tanh_(float x) {
    return __fdividef(2.f, 1.f + __expf(-2.f * x)) - 1.f;
}

// R1-R3 lesson: a per-thread float w[] alloca NEVER gets promoted to VGPRs
// (PromoteAlloca fails on float4-cast fills) -> 35-90GB of scratch traffic.
// Fix: 16 NAMED float4 values (must be register-allocated; ~105 VGPRs live,
// fits the 128-reg budget of waves_per_eu(4,4); LDS pins us to 4 waves/EU).
//
// Bank conflicts (R3: 1.6e9): half-0 reads h[0..63], half-1 reads h[64..127];
// 64 floats = 256B = 0 mod 128B -> same bank quad every access. Fix: rotate
// half-1's float4 order by 4 (IDX below): at each unroll step the halves are
// 16 banks apart -> conflict-free. w and h use the SAME IDX per slot, so the
// dot product pairing is unchanged.
#define IDX(k) (half16 + (((k) + rot) & 15))

#define LOADW(M) do {                                                          \
    const float4* wb4_ = (const float4*)((M) + (size_t)row * HH);              \
    w0  = wb4_[IDX(0)];  w1  = wb4_[IDX(1)];  w2  = wb4_[IDX(2)];              \
    w3  = wb4_[IDX(3)];  w4  = wb4_[IDX(4)];  w5  = wb4_[IDX(5)];              \
    w6  = wb4_[IDX(6)];  w7  = wb4_[IDX(7)];  w8  = wb4_[IDX(8)];              \
    w9  = wb4_[IDX(9)];  w10 = wb4_[IDX(10)]; w11 = wb4_[IDX(11)];             \
    w12 = wb4_[IDX(12)]; w13 = wb4_[IDX(13)]; w14 = wb4_[IDX(14)];             \
    w15 = wb4_[IDX(15)];                                                       \
} while (0)

#define DOT1(h4_, k, W) do { const float4 hv_ = (h4_)[IDX(k)];                 \
    a0 += hv_.x * W.x; a1 += hv_.y * W.y;                                      \
    a2 += hv_.z * W.z; a3 += hv_.w * W.w; } while (0)

#define DOTH(HB) do {                                                          \
    const float4* h4_ = (const float4*)(HB);                                   \
    DOT1(h4_, 0,  w0);  DOT1(h4_, 1,  w1);  DOT1(h4_, 2,  w2);                 \
    DOT1(h4_, 3,  w3);  DOT1(h4_, 4,  w4);  DOT1(h4_, 5,  w5);                 \
    DOT1(h4_, 6,  w6);  DOT1(h4_, 7,  w7);  DOT1(h4_, 8,  w8);                 \
    DOT1(h4_, 9,  w9);  DOT1(h4_, 10, w10); DOT1(h4_, 11, w11);                \
    DOT1(h4_, 12, w12); DOT1(h4_, 13, w13); DOT1(h4_, 14, w14);                \
    DOT1(h4_, 15, w15);                                                        \
} while (0)

extern "C" __global__ void
__attribute__((amdgpu_flat_work_group_size(NT, NT)))
__attribute__((amdgpu_waves_per_eu(4, 4)))
lstm2_fused(const float* __restrict__ x,
            const float* __restrict__ Wih0, const float* __restrict__ Whh0,
            const float* __restrict__ bih0, const float* __restrict__ bhh0,
            const float* __restrict__ Wih1, const float* __restrict__ Whh1,
            const float* __restrict__ bih1, const float* __restrict__ bhh1,
            const float* __restrict__ Wlin, const float* __restrict__ blin,
            float* __restrict__ out)
{
    extern __shared__ float lds[];
    float* h1c  = lds;                    // (TC+1)*HH : h1 ring; row i = h1 at local step i-1
    float* xg1c = h1c + (TC + 1) * HH;    // TC*G4    : layer-1 input gates for the chunk
    float* gbuf = xg1c + TC * G4;         // G4       : activated gates exchange
    float* h2b  = gbuf + G4;              // HH       : current layer-1 hidden
    float* xc   = h2b + HH;               // TC*INW   : x chunk

    const int i      = threadIdx.x;
    const int row    = i >> 1;            // gate row 0..511
    const int half   = i & 1;             // which 64-wide half of the row
    const int half16 = half << 4;         // float4 base of my half
    const int rot    = half << 2;         // bank-conflict rotation
    const int b      = blockIdx.x;

    // half-0 thread of each pair owns bias + x-projection terms
    float bias0 = 0.f, bias1 = 0.f, wx0 = 0.f, wx1 = 0.f, wx2 = 0.f, wx3 = 0.f;
    if (!half) {
        bias0 = bih0[row] + bhh0[row];
        bias1 = bih1[row] + bhh1[row];
        wx0 = Wih0[row*INW+0]; wx1 = Wih0[row*INW+1];
        wx2 = Wih0[row*INW+2]; wx3 = Wih0[row*INW+3];
    }

    // projection params (threads 0..255 = waves 0..3, one output each)
    float wl0 = 0.f, wl1 = 0.f, bl = 0.f;
    if (i < OUTW * 64) {
        const int o = i >> 6, l = i & 63;
        wl0 = Wlin[o*HH + l];
        wl1 = Wlin[o*HH + 64 + l];
        bl  = blin[o];
    }

    float c1 = 0.f, c2 = 0.f;             // cell states (threads i<HH own unit i)
    if (i < HH) { h1c[i] = 0.f; h2b[i] = 0.f; }

    float4 w0, w1, w2, w3, w4, w5, w6, w7, w8, w9, w10, w11, w12, w13, w14, w15;

    const float* xb   = x   + (size_t)b * TT * INW;
    float*       vout = out + (size_t)b * TT * OUTW;
    float*       zout = out + (size_t)BB * TT * OUTW + (size_t)b * HH;

    for (int t0 = 0; t0 < TT; t0 += TC) {
        const int tc = (TT - t0 < TC) ? (TT - t0) : TC;

        if (t0 > 0 && i < HH) h1c[i] = h1c[TC * HH + i];     // carry h1
        for (int j = i; j < tc * INW; j += NT) xc[j] = xb[t0 * INW + j];

        // ================= Phase A: layer-0 recurrence =================
        LOADW(Whh0);
        __syncthreads();

        for (int t = 0; t < tc; ++t) {
            float a0 = 0.f, a1 = 0.f, a2 = 0.f, a3 = 0.f;
            if (!half) {
                const float4 xv = *(const float4*)(xc + t * INW);
                a0 = bias0 + xv.x*wx0 + xv.y*wx1 + xv.z*wx2 + xv.w*wx3;
            }
            DOTH(h1c + t * HH);
            float p = (a0 + a1) + (a2 + a3);
            p += __shfl_xor(p, 1);                           // combine halves
            if (!half) gbuf[row] = ((row >> 7) == 2) ? tanh_(p) : sigm(p);
            __syncthreads();
            if (i < HH) {
                const float gi = gbuf[i],        gf = gbuf[HH + i];
                const float gg = gbuf[2*HH + i], go = gbuf[3*HH + i];
                c1 = gf * c1 + gi * gg;
                h1c[(t + 1) * HH + i] = go * tanh_(c1);
            }
            __syncthreads();
        }

        // ================= Phase B: xg1 = h1 @ Wih1^T + biases =========
        LOADW(Wih1);
        for (int t = 0; t < tc; ++t) {                       // no per-t dependency
            float a0 = half ? 0.f : bias1, a1 = 0.f, a2 = 0.f, a3 = 0.f;
            DOTH(h1c + (t + 1) * HH);
            float p = (a0 + a1) + (a2 + a3);
            p += __shfl_xor(p, 1);
            if (!half) xg1c[t * G4 + row] = p;
        }
        __syncthreads();

        // ====== Phase C: layer-1 recurrence + output projection ========
        LOADW(Whh1);
        for (int t = 0; t < tc; ++t) {
            float a0 = half ? 0.f : xg1c[t * G4 + row];
            float a1 = 0.f, a2 = 0.f, a3 = 0.f;
            DOTH(h2b);
            float p = (a0 + a1) + (a2 + a3);
            p += __shfl_xor(p, 1);
            if (!half) gbuf[row] = ((row >> 7) == 2) ? tanh_(p) : sigm(p);
            __syncthreads();
            if (i < HH) {
                const float gi = gbuf[i],        gf = gbuf[HH + i];
                const float gg = gbuf[2*HH + i], go = gbuf[3*HH + i];
                c2 = gf * c2 + gi * gg;
                h2b[i] = go * tanh_(c2);
            }
            __syncthreads();
            if (i < OUTW * 64) {                             // v[b,t,:] projection
                const int o = i >> 6, l = i & 63;
                float p2 = h2b[l] * wl0 + h2b[64 + l] * wl1;
                p2 += __shfl_xor(p2, 32);
                p2 += __shfl_xor(p2, 16);
                p2 += __shfl_xor(p2, 8);
                p2 += __shfl_xor(p2, 4);
                p2 += __shfl_xor(p2, 2);
                p2 += __shfl_xor(p2, 1);
                if (l == 0) vout[(size_t)(t0 + t) * OUTW + o] = p2 + bl;
            }
        }
        __syncthreads();
    }

    if (i < HH) zout[i] = h2b[i];   // z = zs[:,-1]
}

extern "C" void kernel_launch(void* const* d_in, const int* in_sizes, int n_in,
                              void* d_out, int out_size, void* d_ws, size_t ws_size,
                              hipStream_t stream) {
    const float* x    = (const float*)d_in[0];
    const float* Wih0 = (const float*)d_in[1];
    const float* Whh0 = (const float*)d_in[2];
    const float* bih0 = (const float*)d_in[3];
    const float* bhh0 = (const float*)d_in[4];
    const float* Wih1 = (const float*)d_in[5];
    const float* Whh1 = (const float*)d_in[6];
    const float* bih1 = (const float*)d_in[7];
    const float* bhh1 = (const float*)d_in[8];
    const float* Wlin = (const float*)d_in[9];
    const float* blin = (const float*)d_in[10];
    float* out = (float*)d_out;

    const size_t lds_bytes =
        ((size_t)(TC + 1) * HH + (size_t)TC * G4 + G4 + HH + (size_t)TC * INW) * sizeof(float);

    (void)hipFuncSetAttribute((const void*)lstm2_fused,
                              hipFuncAttributeMaxDynamicSharedMemorySize,
                              (int)lds_bytes);

    lstm2_fused<<<dim3(BB), dim3(NT), lds_bytes, stream>>>(
        x, Wih0, Whh0, bih0, bhh0, Wih1, Whh1, bih1, bhh1, Wlin, blin, out);
}

// Round 5
// 31719.711 us; speedup vs baseline: 1.3471x; 1.3471x over previous
//
#include <hip/hip_runtime.h>

#define BB 256
#define TT 2048
#define HH 128
#define G4 512     // 4*H gate rows
#define INW 4
#define OUTW 4
#define TC 56      // time-chunk; LDS-resident
#define NT 1024    // 2 threads per gate row; 64 weights each
#define HW 64      // half-row width

__device__ __forceinline__ float sigm(float x) {
    return __fdividef(1.f, 1.f + __expf(-x));
}
__device__ __forceinline__ float tanh_(float x) {
    return __fdividef(2.f, 1.f + __expf(-2.f * x)) - 1.f;
}

// R1-R4 lesson: with DYNAMIC shared mem the compiler sees LDS_Block_Size=0,
// assumes 8 waves/EU is reachable, targets 64 VGPRs and spills the weight
// registers to scratch (35-98GB HBM traffic). m97 precedent: static LDS ->
// allocator derives occupancy from LDS -> generous VGPR budget. gfx950 allows
// 160KB static LDS; our 147KB pins 1 WG/CU = 4 waves/EU -> 128-VGPR budget.
//
// Bank conflicts (fixed in R4, keep): half-1's float4 order rotated by 4 so the
// two halves of a row are 16 banks apart at every unroll step.
#define IDX(k) (half16 + (((k) + rot) & 15))

#define LOADW(M) do {                                                          \
    const float4* wb4_ = (const float4*)((M) + (size_t)row * HH);              \
    w0  = wb4_[IDX(0)];  w1  = wb4_[IDX(1)];  w2  = wb4_[IDX(2)];              \
    w3  = wb4_[IDX(3)];  w4  = wb4_[IDX(4)];  w5  = wb4_[IDX(5)];              \
    w6  = wb4_[IDX(6)];  w7  = wb4_[IDX(7)];  w8  = wb4_[IDX(8)];              \
    w9  = wb4_[IDX(9)];  w10 = wb4_[IDX(10)]; w11 = wb4_[IDX(11)];             \
    w12 = wb4_[IDX(12)]; w13 = wb4_[IDX(13)]; w14 = wb4_[IDX(14)];             \
    w15 = wb4_[IDX(15)];                                                       \
} while (0)

#define DOT1(h4_, k, W) do { const float4 hv_ = (h4_)[IDX(k)];                 \
    a0 += hv_.x * W.x; a1 += hv_.y * W.y;                                      \
    a2 += hv_.z * W.z; a3 += hv_.w * W.w; } while (0)

#define DOTH(HB) do {                                                          \
    const float4* h4_ = (const float4*)(HB);                                   \
    DOT1(h4_, 0,  w0);  DOT1(h4_, 1,  w1);  DOT1(h4_, 2,  w2);                 \
    DOT1(h4_, 3,  w3);  DOT1(h4_, 4,  w4);  DOT1(h4_, 5,  w5);                 \
    DOT1(h4_, 6,  w6);  DOT1(h4_, 7,  w7);  DOT1(h4_, 8,  w8);                 \
    DOT1(h4_, 9,  w9);  DOT1(h4_, 10, w10); DOT1(h4_, 11, w11);                \
    DOT1(h4_, 12, w12); DOT1(h4_, 13, w13); DOT1(h4_, 14, w14);                \
    DOT1(h4_, 15, w15);                                                        \
} while (0)

extern "C" __global__ void
__attribute__((amdgpu_flat_work_group_size(NT, NT)))
__attribute__((amdgpu_waves_per_eu(4, 4)))
lstm2_fused(const float* __restrict__ x,
            const float* __restrict__ Wih0, const float* __restrict__ Whh0,
            const float* __restrict__ bih0, const float* __restrict__ bhh0,
            const float* __restrict__ Wih1, const float* __restrict__ Whh1,
            const float* __restrict__ bih1, const float* __restrict__ bhh1,
            const float* __restrict__ Wlin, const float* __restrict__ blin,
            float* __restrict__ out)
{
    // STATIC LDS (147,328 B of 160 KB) — visible to the register allocator.
    __shared__ float h1c[(TC + 1) * HH];  // h1 ring; row i = h1 at local step i-1
    __shared__ float xg1c[TC * G4];       // layer-1 input gates for the chunk
    __shared__ float gbuf[G4];            // activated gates exchange
    __shared__ float h2b[HH];             // current layer-1 hidden
    __shared__ float xc[TC * INW];        // x chunk

    const int i      = threadIdx.x;
    const int row    = i >> 1;            // gate row 0..511
    const int half   = i & 1;             // which 64-wide half of the row
    const int half16 = half << 4;         // float4 base of my half
    const int rot    = half << 2;         // bank-conflict rotation
    const int b      = blockIdx.x;

    // half-0 thread of each pair owns bias + x-projection terms
    float bias0 = 0.f, bias1 = 0.f, wx0 = 0.f, wx1 = 0.f, wx2 = 0.f, wx3 = 0.f;
    if (!half) {
        bias0 = bih0[row] + bhh0[row];
        bias1 = bih1[row] + bhh1[row];
        wx0 = Wih0[row*INW+0]; wx1 = Wih0[row*INW+1];
        wx2 = Wih0[row*INW+2]; wx3 = Wih0[row*INW+3];
    }

    // projection params (threads 0..255 = waves 0..3, one output each)
    float wl0 = 0.f, wl1 = 0.f, bl = 0.f;
    if (i < OUTW * 64) {
        const int o = i >> 6, l = i & 63;
        wl0 = Wlin[o*HH + l];
        wl1 = Wlin[o*HH + 64 + l];
        bl  = blin[o];
    }

    float c1 = 0.f, c2 = 0.f;             // cell states (threads i<HH own unit i)
    if (i < HH) { h1c[i] = 0.f; h2b[i] = 0.f; }

    float4 w0, w1, w2, w3, w4, w5, w6, w7, w8, w9, w10, w11, w12, w13, w14, w15;

    const float* xb   = x   + (size_t)b * TT * INW;
    float*       vout = out + (size_t)b * TT * OUTW;
    float*       zout = out + (size_t)BB * TT * OUTW + (size_t)b * HH;

    for (int t0 = 0; t0 < TT; t0 += TC) {
        const int tc = (TT - t0 < TC) ? (TT - t0) : TC;

        if (t0 > 0 && i < HH) h1c[i] = h1c[TC * HH + i];     // carry h1
        for (int j = i; j < tc * INW; j += NT) xc[j] = xb[t0 * INW + j];

        // ================= Phase A: layer-0 recurrence =================
        LOADW(Whh0);
        __syncthreads();

        for (int t = 0; t < tc; ++t) {
            float a0 = 0.f, a1 = 0.f, a2 = 0.f, a3 = 0.f;
            if (!half) {
                const float4 xv = *(const float4*)(xc + t * INW);
                a0 = bias0 + xv.x*wx0 + xv.y*wx1 + xv.z*wx2 + xv.w*wx3;
            }
            DOTH(h1c + t * HH);
            float p = (a0 + a1) + (a2 + a3);
            p += __shfl_xor(p, 1);                           // combine halves
            if (!half) gbuf[row] = ((row >> 7) == 2) ? tanh_(p) : sigm(p);
            __syncthreads();
            if (i < HH) {
                const float gi = gbuf[i],        gf = gbuf[HH + i];
                const float gg = gbuf[2*HH + i], go = gbuf[3*HH + i];
                c1 = gf * c1 + gi * gg;
                h1c[(t + 1) * HH + i] = go * tanh_(c1);
            }
            __syncthreads();
        }

        // ================= Phase B: xg1 = h1 @ Wih1^T + biases =========
        LOADW(Wih1);
        for (int t = 0; t < tc; ++t) {                       // no per-t dependency
            float a0 = half ? 0.f : bias1, a1 = 0.f, a2 = 0.f, a3 = 0.f;
            DOTH(h1c + (t + 1) * HH);
            float p = (a0 + a1) + (a2 + a3);
            p += __shfl_xor(p, 1);
            if (!half) xg1c[t * G4 + row] = p;
        }
        __syncthreads();

        // ====== Phase C: layer-1 recurrence + output projection ========
        LOADW(Whh1);
        for (int t = 0; t < tc; ++t) {
            float a0 = half ? 0.f : xg1c[t * G4 + row];
            float a1 = 0.f, a2 = 0.f, a3 = 0.f;
            DOTH(h2b);
            float p = (a0 + a1) + (a2 + a3);
            p += __shfl_xor(p, 1);
            if (!half) gbuf[row] = ((row >> 7) == 2) ? tanh_(p) : sigm(p);
            __syncthreads();
            if (i < HH) {
                const float gi = gbuf[i],        gf = gbuf[HH + i];
                const float gg = gbuf[2*HH + i], go = gbuf[3*HH + i];
                c2 = gf * c2 + gi * gg;
                h2b[i] = go * tanh_(c2);
            }
            __syncthreads();
            if (i < OUTW * 64) {                             // v[b,t,:] projection
                const int o = i >> 6, l = i & 63;
                float p2 = h2b[l] * wl0 + h2b[64 + l] * wl1;
                p2 += __shfl_xor(p2, 32);
                p2 += __shfl_xor(p2, 16);
                p2 += __shfl_xor(p2, 8);
                p2 += __shfl_xor(p2, 4);
                p2 += __shfl_xor(p2, 2);
                p2 += __shfl_xor(p2, 1);
                if (l == 0) vout[(size_t)(t0 + t) * OUTW + o] = p2 + bl;
            }
        }
        __syncthreads();
    }

    if (i < HH) zout[i] = h2b[i];   // z = zs[:,-1]
}

extern "C" void kernel_launch(void* const* d_in, const int* in_sizes, int n_in,
                              void* d_out, int out_size, void* d_ws, size_t ws_size,
                              hipStream_t stream) {
    const float* x    = (const float*)d_in[0];
    const float* Wih0 = (const float*)d_in[1];
    const float* Whh0 = (const float*)d_in[2];
    const float* bih0 = (const float*)d_in[3];
    const float* bhh0 = (const float*)d_in[4];
    const float* Wih1 = (const float*)d_in[5];
    const float* Whh1 = (const float*)d_in[6];
    const float* bih1 = (const float*)d_in[7];
    const float* bhh1 = (const float*)d_in[8];
    const float* Wlin = (const float*)d_in[9];
    const float* blin = (const float*)d_in[10];
    float* out = (float*)d_out;

    lstm2_fused<<<dim3(BB), dim3(NT), 0, stream>>>(
        x, Wih0, Whh0, bih0, bhh0, Wih1, Whh1, bih1, bhh1, Wlin, blin, out);
}

// Round 6
// 6782.126 us; speedup vs baseline: 6.3003x; 4.6770x over previous
//
#include <hip/hip_runtime.h>

#define BB 256
#define TT 2048
#define HH 128
#define G4 512     // 4*H gate rows
#define INW 4
#define OUTW 4
#define TC 56      // time-chunk; LDS-resident
#define NT 1024    // 2 threads per gate row; 64 weights each
#define HW 64      // half-row width

typedef _Float16 f16x2 __attribute__((ext_vector_type(2)));

__device__ __forceinline__ float sigm(float x) {
    return __fdividef(1.f, 1.f + __expf(-x));
}
__device__ __forceinline__ float tanh_(float x) {
    return __fdividef(2.f, 1.f + __expf(-2.f * x)) - 1.f;
}

// R1-R5 lesson: the backend budgets VGPRs for 2 workgroups/CU no matter what
// (NT=1024 -> 64 VGPRs), ignoring waves_per_eu / launch_bounds / static-LDS
// occupancy. 64 fp32 weights + ~35 working regs never fits -> permanent spill,
// 35-98GB scratch traffic. Fix: halve the weight footprint — store the 64
// weights as 32 packed-f16 regs, convert at use (fp32 accumulate; h, gates,
// cell, Wlin stay fp32). Demand ~58 regs < 64 -> no spill.
//
// Guard 1 (KEEP): empty asm redefines the 32 packed regs each t-iteration so
// LICM cannot hoist the 64 loop-invariant f16->f32 converts back out (which
// would recreate the 64-float pressure).
// Guard 2: sched_barrier(0x124) (DS_READ|VMEM_READ|SALU may cross, VALU not)
// every 4 MACs stops the MIR scheduler from clustering converts.
//
// Bank conflicts (fixed in R4, keep): half-1's float4 order rotated by 4 so the
// two halves of a row are 16 banks apart at every unroll step.
#define IDX(k) (half16 + (((k) + rot) & 15))

#define CVT2(dlo, dhi, f4_)                                                    \
    dlo = (f16x2){(_Float16)(f4_).x, (_Float16)(f4_).y};                       \
    dhi = (f16x2){(_Float16)(f4_).z, (_Float16)(f4_).w}

#define LOADW(M) do {                                                          \
    const float4* wb4_ = (const float4*)((M) + (size_t)row * HH);              \
    float4 t_;                                                                 \
    t_ = wb4_[IDX(0)];  CVT2(wl0,  wh0,  t_);                                  \
    t_ = wb4_[IDX(1)];  CVT2(wl1,  wh1,  t_);                                  \
    t_ = wb4_[IDX(2)];  CVT2(wl2,  wh2,  t_);                                  \
    t_ = wb4_[IDX(3)];  CVT2(wl3,  wh3,  t_);                                  \
    t_ = wb4_[IDX(4)];  CVT2(wl4,  wh4,  t_);                                  \
    t_ = wb4_[IDX(5)];  CVT2(wl5,  wh5,  t_);                                  \
    t_ = wb4_[IDX(6)];  CVT2(wl6,  wh6,  t_);                                  \
    t_ = wb4_[IDX(7)];  CVT2(wl7,  wh7,  t_);                                  \
    t_ = wb4_[IDX(8)];  CVT2(wl8,  wh8,  t_);                                  \
    t_ = wb4_[IDX(9)];  CVT2(wl9,  wh9,  t_);                                  \
    t_ = wb4_[IDX(10)]; CVT2(wl10, wh10, t_);                                  \
    t_ = wb4_[IDX(11)]; CVT2(wl11, wh11, t_);                                  \
    t_ = wb4_[IDX(12)]; CVT2(wl12, wh12, t_);                                  \
    t_ = wb4_[IDX(13)]; CVT2(wl13, wh13, t_);                                  \
    t_ = wb4_[IDX(14)]; CVT2(wl14, wh14, t_);                                  \
    t_ = wb4_[IDX(15)]; CVT2(wl15, wh15, t_);                                  \
} while (0)

// redefine all packed-weight regs: blocks loop-invariant hoisting of converts
#define KEEP() asm volatile(""                                                 \
    : "+v"(wl0),  "+v"(wl1),  "+v"(wl2),  "+v"(wl3),                           \
      "+v"(wl4),  "+v"(wl5),  "+v"(wl6),  "+v"(wl7),                           \
      "+v"(wl8),  "+v"(wl9),  "+v"(wl10), "+v"(wl11),                          \
      "+v"(wl12), "+v"(wl13), "+v"(wl14), "+v"(wl15),                          \
      "+v"(wh0),  "+v"(wh1),  "+v"(wh2),  "+v"(wh3),                           \
      "+v"(wh4),  "+v"(wh5),  "+v"(wh6),  "+v"(wh7),                           \
      "+v"(wh8),  "+v"(wh9),  "+v"(wh10), "+v"(wh11),                          \
      "+v"(wh12), "+v"(wh13), "+v"(wh14), "+v"(wh15))

#define DOT1(k, WL, WH) do { const float4 hv_ = h4_[IDX(k)];                   \
    a0 += (float)WL.x * hv_.x; a1 += (float)WL.y * hv_.y;                      \
    a2 += (float)WH.x * hv_.z; a3 += (float)WH.y * hv_.w;                      \
    __builtin_amdgcn_sched_barrier(0x124); } while (0)

#define DOTH(HB) do {                                                          \
    const float4* h4_ = (const float4*)(HB);                                   \
    DOT1(0,  wl0,  wh0);  DOT1(1,  wl1,  wh1);  DOT1(2,  wl2,  wh2);           \
    DOT1(3,  wl3,  wh3);  DOT1(4,  wl4,  wh4);  DOT1(5,  wl5,  wh5);           \
    DOT1(6,  wl6,  wh6);  DOT1(7,  wl7,  wh7);  DOT1(8,  wl8,  wh8);           \
    DOT1(9,  wl9,  wh9);  DOT1(10, wl10, wh10); DOT1(11, wl11, wh11);          \
    DOT1(12, wl12, wh12); DOT1(13, wl13, wh13); DOT1(14, wl14, wh14);          \
    DOT1(15, wl15, wh15);                                                      \
} while (0)

extern "C" __global__ void
__attribute__((amdgpu_flat_work_group_size(NT, NT)))
__attribute__((amdgpu_waves_per_eu(4, 4)))
lstm2_fused(const float* __restrict__ x,
            const float* __restrict__ Wih0, const float* __restrict__ Whh0,
            const float* __restrict__ bih0, const float* __restrict__ bhh0,
            const float* __restrict__ Wih1, const float* __restrict__ Whh1,
            const float* __restrict__ bih1, const float* __restrict__ bhh1,
            const float* __restrict__ Wlin, const float* __restrict__ blin,
            float* __restrict__ out)
{
    // STATIC LDS (147,328 B of 160 KB)
    __shared__ float h1c[(TC + 1) * HH];  // h1 ring; row i = h1 at local step i-1
    __shared__ float xg1c[TC * G4];       // layer-1 input gates for the chunk
    __shared__ float gbuf[G4];            // activated gates exchange
    __shared__ float h2b[HH];             // current layer-1 hidden
    __shared__ float xc[TC * INW];        // x chunk

    const int i      = threadIdx.x;
    const int row    = i >> 1;            // gate row 0..511
    const int half   = i & 1;             // which 64-wide half of the row
    const int half16 = half << 4;         // float4 base of my half
    const int rot    = half << 2;         // bank-conflict rotation
    const int b      = blockIdx.x;

    // half-0 thread of each pair owns bias + x-projection terms
    float bias0 = 0.f, bias1 = 0.f, wx0 = 0.f, wx1 = 0.f, wx2 = 0.f, wx3 = 0.f;
    if (!half) {
        bias0 = bih0[row] + bhh0[row];
        bias1 = bih1[row] + bhh1[row];
        wx0 = Wih0[row*INW+0]; wx1 = Wih0[row*INW+1];
        wx2 = Wih0[row*INW+2]; wx3 = Wih0[row*INW+3];
    }

    // projection params (threads 0..255 = waves 0..3, one output each)
    float wl_0 = 0.f, wl_1 = 0.f, bl = 0.f;
    if (i < OUTW * 64) {
        const int o = i >> 6, l = i & 63;
        wl_0 = Wlin[o*HH + l];
        wl_1 = Wlin[o*HH + 64 + l];
        bl   = blin[o];
    }

    float c1 = 0.f, c2 = 0.f;             // cell states (threads i<HH own unit i)
    if (i < HH) { h1c[i] = 0.f; h2b[i] = 0.f; }

    f16x2 wl0, wl1, wl2, wl3, wl4, wl5, wl6, wl7,
          wl8, wl9, wl10, wl11, wl12, wl13, wl14, wl15;
    f16x2 wh0, wh1, wh2, wh3, wh4, wh5, wh6, wh7,
          wh8, wh9, wh10, wh11, wh12, wh13, wh14, wh15;

    const float* xb   = x   + (size_t)b * TT * INW;
    float*       vout = out + (size_t)b * TT * OUTW;
    float*       zout = out + (size_t)BB * TT * OUTW + (size_t)b * HH;

    for (int t0 = 0; t0 < TT; t0 += TC) {
        const int tc = (TT - t0 < TC) ? (TT - t0) : TC;

        if (t0 > 0 && i < HH) h1c[i] = h1c[TC * HH + i];     // carry h1
        for (int j = i; j < tc * INW; j += NT) xc[j] = xb[t0 * INW + j];

        // ================= Phase A: layer-0 recurrence =================
        LOADW(Whh0);
        __syncthreads();

        for (int t = 0; t < tc; ++t) {
            KEEP();
            float a0 = 0.f, a1 = 0.f, a2 = 0.f, a3 = 0.f;
            if (!half) {
                const float4 xv = *(const float4*)(xc + t * INW);
                a0 = bias0 + xv.x*wx0 + xv.y*wx1 + xv.z*wx2 + xv.w*wx3;
            }
            DOTH(h1c + t * HH);
            float p = (a0 + a1) + (a2 + a3);
            p += __shfl_xor(p, 1);                           // combine halves
            if (!half) gbuf[row] = ((row >> 7) == 2) ? tanh_(p) : sigm(p);
            __syncthreads();
            if (i < HH) {
                const float gi = gbuf[i],        gf = gbuf[HH + i];
                const float gg = gbuf[2*HH + i], go = gbuf[3*HH + i];
                c1 = gf * c1 + gi * gg;
                h1c[(t + 1) * HH + i] = go * tanh_(c1);
            }
            __syncthreads();
        }

        // ================= Phase B: xg1 = h1 @ Wih1^T + biases =========
        LOADW(Wih1);
        for (int t = 0; t < tc; ++t) {                       // no per-t dependency
            KEEP();
            float a0 = half ? 0.f : bias1, a1 = 0.f, a2 = 0.f, a3 = 0.f;
            DOTH(h1c + (t + 1) * HH);
            float p = (a0 + a1) + (a2 + a3);
            p += __shfl_xor(p, 1);
            if (!half) xg1c[t * G4 + row] = p;
        }
        __syncthreads();

        // ====== Phase C: layer-1 recurrence + output projection ========
        LOADW(Whh1);
        for (int t = 0; t < tc; ++t) {
            KEEP();
            float a0 = half ? 0.f : xg1c[t * G4 + row];
            float a1 = 0.f, a2 = 0.f, a3 = 0.f;
            DOTH(h2b);
            float p = (a0 + a1) + (a2 + a3);
            p += __shfl_xor(p, 1);
            if (!half) gbuf[row] = ((row >> 7) == 2) ? tanh_(p) : sigm(p);
            __syncthreads();
            if (i < HH) {
                const float gi = gbuf[i],        gf = gbuf[HH + i];
                const float gg = gbuf[2*HH + i], go = gbuf[3*HH + i];
                c2 = gf * c2 + gi * gg;
                h2b[i] = go * tanh_(c2);
            }
            __syncthreads();
            if (i < OUTW * 64) {                             // v[b,t,:] projection
                const int o = i >> 6, l = i & 63;
                float p2 = h2b[l] * wl_0 + h2b[64 + l] * wl_1;
                p2 += __shfl_xor(p2, 32);
                p2 += __shfl_xor(p2, 16);
                p2 += __shfl_xor(p2, 8);
                p2 += __shfl_xor(p2, 4);
                p2 += __shfl_xor(p2, 2);
                p2 += __shfl_xor(p2, 1);
                if (l == 0) vout[(size_t)(t0 + t) * OUTW + o] = p2 + bl;
            }
        }
        __syncthreads();
    }

    if (i < HH) zout[i] = h2b[i];   // z = zs[:,-1]
}

extern "C" void kernel_launch(void* const* d_in, const int* in_sizes, int n_in,
                              void* d_out, int out_size, void* d_ws, size_t ws_size,
                              hipStream_t stream) {
    const float* x    = (const float*)d_in[0];
    const float* Wih0 = (const float*)d_in[1];
    const float* Whh0 = (const float*)d_in[2];
    const float* bih0 = (const float*)d_in[3];
    const float* bhh0 = (const float*)d_in[4];
    const float* Wih1 = (const float*)d_in[5];
    const float* Whh1 = (const float*)d_in[6];
    const float* bih1 = (const float*)d_in[7];
    const float* bhh1 = (const float*)d_in[8];
    const float* Wlin = (const float*)d_in[9];
    const float* blin = (const float*)d_in[10];
    float* out = (float*)d_out;

    lstm2_fused<<<dim3(BB), dim3(NT), 0, stream>>>(
        x, Wih0, Whh0, bih0, bhh0, Wih1, Whh1, bih1, bhh1, Wlin, blin, out);
}

// Round 7
// 6315.466 us; speedup vs baseline: 6.7659x; 1.0739x over previous
//
#include <hip/hip_runtime.h>

#define BB 256
#define TT 2048
#define HH 128
#define G4 512     // 4*H gate rows
#define INW 4
#define OUTW 4
#define TC 56      // time-chunk; LDS-resident (2048 = 36*56 + 32, both even)
#define NT 1024
#define HW 64      // half-row width

typedef _Float16 f16x2 __attribute__((ext_vector_type(2)));
typedef _Float16 f16x8 __attribute__((ext_vector_type(8)));

#if __has_builtin(__builtin_amdgcn_fdot2)
#define FDOT2(a, b, c) __builtin_amdgcn_fdot2((a), (b), (c), false)
#else
#define FDOT2(a, b, c) ((c) + (float)(a).x * (float)(b).x + (float)(a).y * (float)(b).y)
#endif

__device__ __forceinline__ float sigm(float x) {
    return __fdividef(1.f, 1.f + __expf(-x));
}
__device__ __forceinline__ float tanh_(float x) {
    return __fdividef(2.f, 1.f + __expf(-2.f * x)) - 1.f;
}

// R6 lesson: f16 weights via named regs fixed the spill (FETCH 84GB -> 12MB).
// R7: VALU was burning 64 cvt + 64 fma per t-phase; h now stored f16 in LDS and
// consumed by v_dot2_f32_f16 (fp32 accum): 32 dot2 + 8 ds_read_b128 per t-phase.
// Row remap i = u*8 + g*2 + half puts a unit's 4 gates in 8 adjacent lanes:
// gate exchange = 1 shfl_xor + 4 shfl (no LDS gbuf, no serial 2-wave phase),
// cell state replicated across the 8 lanes. One barrier per step (h1 ring is
// time-indexed; h2 double-buffered by step parity). Budget stays 64 VGPR
// (backend assumes 2 WG/CU at NT=1024); live ~60 -> no spill. Watch FETCH.

#define PAIR(hv, j) __builtin_shufflevector((hv), (hv), 2*(j), 2*(j)+1)

#define DOTK(k, W0, W1, W2, W3) do { const f16x8 hv_ = hp_[k];                 \
    a0 = FDOT2(W0, PAIR(hv_, 0), a0);                                          \
    a1 = FDOT2(W1, PAIR(hv_, 1), a1);                                          \
    a2 = FDOT2(W2, PAIR(hv_, 2), a2);                                          \
    a3 = FDOT2(W3, PAIR(hv_, 3), a3); } while (0)

#define DOTH(HB) do { const f16x8* hp_ = (const f16x8*)(HB);                   \
    DOTK(0,  w0,  w1,  w2,  w3);  DOTK(1,  w4,  w5,  w6,  w7);                 \
    DOTK(2,  w8,  w9,  w10, w11); DOTK(3,  w12, w13, w14, w15);                \
    DOTK(4,  w16, w17, w18, w19); DOTK(5,  w20, w21, w22, w23);                \
    DOTK(6,  w24, w25, w26, w27); DOTK(7,  w28, w29, w30, w31); } while (0)

#define LW2(m, WA, WB) { const float4 t_ = wb_[m];                             \
    WA = (f16x2){(_Float16)t_.x, (_Float16)t_.y};                              \
    WB = (f16x2){(_Float16)t_.z, (_Float16)t_.w}; }

#define LOADW(M) do {                                                          \
    const float4* wb_ = (const float4*)((M) + (size_t)r * HH + hoff);          \
    LW2(0,  w0,  w1);  LW2(1,  w2,  w3);  LW2(2,  w4,  w5);                    \
    LW2(3,  w6,  w7);  LW2(4,  w8,  w9);  LW2(5,  w10, w11);                   \
    LW2(6,  w12, w13); LW2(7,  w14, w15); LW2(8,  w16, w17);                   \
    LW2(9,  w18, w19); LW2(10, w20, w21); LW2(11, w22, w23);                   \
    LW2(12, w24, w25); LW2(13, w26, w27); LW2(14, w28, w29);                   \
    LW2(15, w30, w31);                                                         \
} while (0)

extern "C" __global__ void
__attribute__((amdgpu_flat_work_group_size(NT, NT)))
__attribute__((amdgpu_waves_per_eu(4, 4)))
lstm2_fused(const float* __restrict__ x,
            const float* __restrict__ Wih0, const float* __restrict__ Whh0,
            const float* __restrict__ bih0, const float* __restrict__ bhh0,
            const float* __restrict__ Wih1, const float* __restrict__ Whh1,
            const float* __restrict__ bih1, const float* __restrict__ bhh1,
            const float* __restrict__ Wlin, const float* __restrict__ blin,
            float* __restrict__ out)
{
    // STATIC LDS: 130,688 B of 160 KB
    __shared__ _Float16 h1h[(TC + 1) * HH];  // h1 ring (f16); row i = h1 at local step i-1
    __shared__ float    xg1c[TC * G4];       // layer-1 input gates (fp32)
    __shared__ _Float16 h2h[2 * HH];         // h2 double buffer (f16), parity = t&1
    __shared__ float    xc[TC * INW];        // x chunk

    const int i     = threadIdx.x;
    const int half  = i & 1;                 // half of the row
    const int g     = (i >> 1) & 3;          // gate (0=i,1=f,2=g,3=o)
    const int u     = i >> 3;                // unit 0..127
    const int r     = (g << 7) | u;          // gate row 0..511
    const int hoff  = half * HW;
    const int gbase = i & 56;                // lane base of my unit's 8-lane group
    const int b     = blockIdx.x;

    float bias0 = 0.f, bias1 = 0.f, wx0 = 0.f, wx1 = 0.f, wx2 = 0.f, wx3 = 0.f;
    if (!half) {
        bias0 = bih0[r] + bhh0[r];
        bias1 = bih1[r] + bhh1[r];
        wx0 = Wih0[r*INW+0]; wx1 = Wih0[r*INW+1];
        wx2 = Wih0[r*INW+2]; wx3 = Wih0[r*INW+3];
    }

    float wlA = 0.f, wlB = 0.f, bl = 0.f;    // projection (threads 0..255)
    if (i < OUTW * 64) {
        const int o = i >> 6, l = i & 63;
        wlA = Wlin[o*HH + l];
        wlB = Wlin[o*HH + 64 + l];
        bl  = blin[o];
    }

    float c1 = 0.f, c2 = 0.f;                // cell state, replicated per 8-lane unit group
    if (i < HH) { h1h[i] = (_Float16)0.f; h2h[i] = (_Float16)0.f; }

    f16x2 w0,  w1,  w2,  w3,  w4,  w5,  w6,  w7,
          w8,  w9,  w10, w11, w12, w13, w14, w15,
          w16, w17, w18, w19, w20, w21, w22, w23,
          w24, w25, w26, w27, w28, w29, w30, w31;

    const float* xb   = x   + (size_t)b * TT * INW;
    float*       vout = out + (size_t)b * TT * OUTW;
    float*       zout = out + (size_t)BB * TT * OUTW + (size_t)b * HH;

    for (int t0 = 0; t0 < TT; t0 += TC) {
        const int tc = (TT - t0 < TC) ? (TT - t0) : TC;

        if (t0 > 0 && i < HH) h1h[i] = h1h[TC * HH + i];   // carry h1 ring
        for (int j = i; j < tc * INW; j += NT) xc[j] = xb[t0 * INW + j];

        // ================= Phase A: layer-0 recurrence =================
        LOADW(Whh0);
        __syncthreads();

        for (int t = 0; t < tc; ++t) {
            float a0 = 0.f, a1 = 0.f, a2 = 0.f, a3 = 0.f;
            if (!half) {
                const float4 xv = *(const float4*)(xc + t * INW);
                a0 = bias0 + xv.x*wx0 + xv.y*wx1 + xv.z*wx2 + xv.w*wx3;
            }
            DOTH(h1h + t * HH + hoff);
            float p = (a0 + a1) + (a2 + a3);
            p += __shfl_xor(p, 1);                         // combine halves
            const float act = (g == 2) ? tanh_(p) : sigm(p);
            const float A0 = __shfl(act, gbase);           // i-gate (from half0 lanes)
            const float A1 = __shfl(act, gbase | 2);       // f
            const float A2 = __shfl(act, gbase | 4);       // g
            const float A3 = __shfl(act, gbase | 6);       // o
            c1 = A1 * c1 + A0 * A2;
            const float hn = A3 * tanh_(c1);
            if ((i & 7) == 0) h1h[(t + 1) * HH + u] = (_Float16)hn;
            __syncthreads();
        }

        // ================= Phase B: xg1 = h1 @ Wih1^T + biases =========
        LOADW(Wih1);
        for (int t = 0; t < tc; ++t) {                     // no per-t dependency
            float a0 = half ? 0.f : bias1, a1 = 0.f, a2 = 0.f, a3 = 0.f;
            DOTH(h1h + (t + 1) * HH + hoff);
            float p = (a0 + a1) + (a2 + a3);
            p += __shfl_xor(p, 1);
            if (!half) xg1c[t * G4 + r] = p;
        }
        __syncthreads();

        // ====== Phase C: layer-1 recurrence + output projection ========
        LOADW(Whh1);
        for (int t = 0; t < tc; ++t) {
            const int rb = (t & 1) * HH;                   // read buffer
            const int wb = rb ^ HH;                        // write buffer
            float a0 = half ? 0.f : xg1c[t * G4 + r];
            float a1 = 0.f, a2 = 0.f, a3 = 0.f;
            DOTH(h2h + rb + hoff);
            float p = (a0 + a1) + (a2 + a3);
            p += __shfl_xor(p, 1);
            const float act = (g == 2) ? tanh_(p) : sigm(p);
            const float A0 = __shfl(act, gbase);
            const float A1 = __shfl(act, gbase | 2);
            const float A2 = __shfl(act, gbase | 4);
            const float A3 = __shfl(act, gbase | 6);
            c2 = A1 * c2 + A0 * A2;
            const float hn = A3 * tanh_(c2);
            if ((i & 7) == 0) {
                h2h[wb + u] = (_Float16)hn;
                if (t0 + t == TT - 1) zout[u] = hn;        // z = zs[:,-1], fp32-exact
            }
            __syncthreads();
            if (i < OUTW * 64) {                           // projection from fresh h2
                const int l = i & 63;
                float p2 = (float)h2h[wb + l] * wlA + (float)h2h[wb + 64 + l] * wlB;
                p2 += __shfl_xor(p2, 32);
                p2 += __shfl_xor(p2, 16);
                p2 += __shfl_xor(p2, 8);
                p2 += __shfl_xor(p2, 4);
                p2 += __shfl_xor(p2, 2);
                p2 += __shfl_xor(p2, 1);
                if (l == 0) vout[(size_t)(t0 + t) * OUTW + (i >> 6)] = p2 + bl;
            }
        }
        // next chunk's staging writes (h1h row0, xc) are disjoint from the
        // projection reads above; the chunk-top __syncthreads gates phase A.
    }
}

extern "C" void kernel_launch(void* const* d_in, const int* in_sizes, int n_in,
                              void* d_out, int out_size, void* d_ws, size_t ws_size,
                              hipStream_t stream) {
    const float* x    = (const float*)d_in[0];
    const float* Wih0 = (const float*)d_in[1];
    const float* Whh0 = (const float*)d_in[2];
    const float* bih0 = (const float*)d_in[3];
    const float* bhh0 = (const float*)d_in[4];
    const float* Wih1 = (const float*)d_in[5];
    const float* Whh1 = (const float*)d_in[6];
    const float* bih1 = (const float*)d_in[7];
    const float* bhh1 = (const float*)d_in[8];
    const float* Wlin = (const float*)d_in[9];
    const float* blin = (const float*)d_in[10];
    float* out = (float*)d_out;

    lstm2_fused<<<dim3(BB), dim3(NT), 0, stream>>>(
        x, Wih0, Whh0, bih0, bhh0, Wih1, Whh1, bih1, bhh1, Wlin, blin, out);
}